// Round 4
// baseline (200.364 us; speedup 1.0000x reference)
//
#include <hip/hip_runtime.h>
#include <hip/hip_bf16.h>

// Problem constants (B=4, S=4096, A=2, H=8, DH=128, DM=2048)
#define T_TOK 16384
#define NH 8
#define DHD 128
#define DMD 2048
#define NBUCKET 64
#define KTOT 256          // A=2 slots * DH=128
#define NPACK 2064        // (T_TOK+128)*32/256 pack blocks

typedef __attribute__((ext_vector_type(8))) short bf16x8;
typedef __attribute__((ext_vector_type(4))) float f32x4;

__device__ inline short f2b(float x) {
    __hip_bfloat16 h = __float2bfloat16(x);
    return *reinterpret_cast<short*>(&h);
}

// ---------------- ws layout (bytes) ----------------
// 0       : hist[64]     (zeroed each call by k_init)
// 256     : offsets[64]
// 512     : cursor[64]   (zeroed each call by k_init)
// 768     : ntiles
// 1024    : tiles[256][4] int (4 KB)
// 8192    : keys[16384]  (64 KB)
// 73728   : perm[16384]  (64 KB)
// 262144  : Wt  bf16 [8][2048][128]        (4 MB)
// 4456448 : Apk bf16 [16384+128][256]      (8.45 MB)

__global__ void k_init(int* __restrict__ ctrl) {
    ctrl[threadIdx.x] = 0;   // 256 threads x 4B = 1024 B
}

__global__ void k_keys(const int* __restrict__ idx, int* __restrict__ keys,
                       int* __restrict__ hist) {
    int t = blockIdx.x * 256 + threadIdx.x;
    if (t < T_TOK) {
        int key = idx[2 * t] * NH + idx[2 * t + 1];
        keys[t] = key;
        atomicAdd(&hist[key], 1);
    }
}

// parallel scan: 1 wave, 64 buckets. Prefix-sums via shfl_up; tile list
// built per-bucket (order irrelevant — tiles write disjoint out rows).
__global__ void k_scan(const int* __restrict__ hist, int* __restrict__ offs,
                       int* __restrict__ tiles, int* __restrict__ ntiles) {
    int k = threadIdx.x;  // 0..63
    int n = hist[k];
    int x = n;
#pragma unroll
    for (int d = 1; d < 64; d <<= 1) {
        int v = __shfl_up(x, d, 64);
        if (k >= d) x += v;
    }
    int off = x - n;
    offs[k] = off;
    int tk = (n + 127) >> 7;
    int y = tk;
#pragma unroll
    for (int d = 1; d < 64; d <<= 1) {
        int v = __shfl_up(y, d, 64);
        if (k >= d) y += v;
    }
    int tbase = y - tk;
    for (int s = 0; s < tk; ++s) {
        int nt = tbase + s;
        tiles[4 * nt + 0] = k;
        tiles[4 * nt + 1] = off + s * 128;
        int rem = n - s * 128;
        tiles[4 * nt + 2] = rem < 128 ? rem : 128;
        tiles[4 * nt + 3] = 0;
    }
    if (k == 63) *ntiles = y;
}

__global__ void k_scatter(const int* __restrict__ keys, const int* __restrict__ offs,
                          int* __restrict__ cursor, int* __restrict__ perm) {
    int t = blockIdx.x * 256 + threadIdx.x;
    if (t < T_TOK) {
        int key = keys[t];
        int pos = offs[key] + atomicAdd(&cursor[key], 1);
        perm[pos] = t;
    }
}

// merged prep: blocks [0,NPACK) build Apk (routed, prob-scaled bf16 A);
// blocks [NPACK, NPACK+256) transpose W -> Wt bf16 [h][m][d].
__global__ __launch_bounds__(256) void k_prep(
    const float* __restrict__ emb, const float* __restrict__ probs,
    const int* __restrict__ perm, const float* __restrict__ W,
    short* __restrict__ Apk, short* __restrict__ Wt) {
    if (blockIdx.x < NPACK) {
        int gid = blockIdx.x * 256 + threadIdx.x;  // one 16B chunk each
        int pos = gid >> 5;
        int k0  = (gid & 31) * 8;
        short* dst = Apk + (size_t)pos * KTOT + k0;
        if (pos >= T_TOK) {  // zero slack rows (tiles may read past last row)
            bf16x8 z;
#pragma unroll
            for (int j = 0; j < 8; ++j) z[j] = 0;
            *(bf16x8*)dst = z;
            return;
        }
        int t = perm[pos];
        int a = k0 >> 7;
        float p = probs[2 * t + a];
        const float* src = emb + ((size_t)(2 * t + a)) * DHD + (k0 & 127);
        f32x4 f0 = ((const f32x4*)src)[0];
        f32x4 f1 = ((const f32x4*)src)[1];
        bf16x8 o;
        o[0] = f2b(p * f0.x); o[1] = f2b(p * f0.y);
        o[2] = f2b(p * f0.z); o[3] = f2b(p * f0.w);
        o[4] = f2b(p * f1.x); o[5] = f2b(p * f1.y);
        o[6] = f2b(p * f1.z); o[7] = f2b(p * f1.w);
        *(bf16x8*)dst = o;
    } else {
        __shared__ float Ws[DHD][65];
        int bx = blockIdx.x - NPACK;
        int h = bx >> 5, m0 = (bx & 31) * 64;
        int tid = threadIdx.x;
        for (int i = tid; i < DHD * 64; i += 256) {
            int d = i >> 6, m = i & 63;
            Ws[d][m] = W[((size_t)h * DHD + d) * DMD + m0 + m];
        }
        __syncthreads();
        for (int i = tid; i < 64 * 16; i += 256) {
            int m = i >> 4, d0 = (i & 15) * 8;
            bf16x8 o;
#pragma unroll
            for (int j = 0; j < 8; ++j) o[j] = f2b(Ws[d0 + j][m]);
            *(bf16x8*)(Wt + ((size_t)h * DMD + m0 + m) * DHD + d0) = o;
        }
    }
}

// LDS-free GEMM: A (Apk) and B (Wt) are already in MFMA fragment layout,
// so each fragment is one 16B contiguous global load (16 rows x 64B
// segments per instruction, L2/L3-resident). No staging, no K-loop
// barriers -> deep MLP across 12-16 waves/CU.
__global__ __launch_bounds__(256) void k_gemm(
    const short* __restrict__ Apk, const float* __restrict__ probs,
    const short* __restrict__ Wt, const float* __restrict__ bias,
    const int* __restrict__ perm, const int* __restrict__ tiles,
    const int* __restrict__ ntiles, float* __restrict__ out) {
    int tile_id = blockIdx.y;
    if (tile_id >= *ntiles) return;
    int key   = tiles[4 * tile_id + 0];
    int row0  = tiles[4 * tile_id + 1];
    int nrows = tiles[4 * tile_id + 2];
    int h0 = key >> 3, h1 = key & 7;
    int ncol = blockIdx.x * 128;

    __shared__ int   s_tok[128];
    __shared__ float s_p0[128], s_p1[128];

    int tid = threadIdx.x;
    int lane = tid & 63, wave = tid >> 6;
    int l15 = lane & 15, lq = lane >> 4;
    int wm = (wave >> 1) * 64, wn = (wave & 1) * 64;

    if (tid < 128) {
        int t = -1; float p0 = 0.f, p1 = 0.f;
        if (tid < nrows) {
            t = perm[row0 + tid];
            p0 = probs[2 * t];
            p1 = probs[2 * t + 1];
        }
        s_tok[tid] = t; s_p0[tid] = p0; s_p1[tid] = p1;
    }
    __syncthreads();

    f32x4 acc[4][4];
#pragma unroll
    for (int i = 0; i < 4; ++i)
#pragma unroll
        for (int j = 0; j < 4; ++j) acc[i][j] = (f32x4){0.f, 0.f, 0.f, 0.f};

    // per-lane fragment bases
    const short* abase[4];
    const short* bb0[4];
    const short* bb1[4];
#pragma unroll
    for (int mi = 0; mi < 4; ++mi)
        abase[mi] = Apk + (size_t)(row0 + wm + mi * 16 + l15) * KTOT + lq * 8;
#pragma unroll
    for (int ni = 0; ni < 4; ++ni) {
        size_t roff = (size_t)(ncol + wn + ni * 16 + l15) * DHD + lq * 8;
        bb0[ni] = Wt + (size_t)h0 * DMD * DHD + roff;
        bb1[ni] = Wt + (size_t)h1 * DMD * DHD + roff;
    }

#pragma unroll 2
    for (int ki = 0; ki < 8; ++ki) {
        int ko = (ki & 3) * 32;
        bf16x8 af[4], bfr[4];
#pragma unroll
        for (int mi = 0; mi < 4; ++mi)
            af[mi] = *(const bf16x8*)(abase[mi] + ki * 32);
#pragma unroll
        for (int ni = 0; ni < 4; ++ni)
            bfr[ni] = *(const bf16x8*)((ki < 4 ? bb0[ni] : bb1[ni]) + ko);
#pragma unroll
        for (int mi = 0; mi < 4; ++mi)
#pragma unroll
            for (int ni = 0; ni < 4; ++ni)
                acc[mi][ni] = __builtin_amdgcn_mfma_f32_16x16x32_bf16(
                    af[mi], bfr[ni], acc[mi][ni], 0, 0, 0);
    }

    // epilogue: prob-weighted bias, scatter rows to out
#pragma unroll
    for (int ni = 0; ni < 4; ++ni) {
        int c = ncol + wn + ni * 16 + l15;
        float b0 = bias[h0 * DMD + c];
        float b1 = bias[h1 * DMD + c];
#pragma unroll
        for (int mi = 0; mi < 4; ++mi) {
#pragma unroll
            for (int r = 0; r < 4; ++r) {
                int i = wm + mi * 16 + lq * 4 + r;
                int t = s_tok[i];
                if (t >= 0) {
                    out[(size_t)t * DMD + c] =
                        acc[mi][ni][r] + s_p0[i] * b0 + s_p1[i] * b1;
                }
            }
        }
    }
}

extern "C" void kernel_launch(void* const* d_in, const int* in_sizes, int n_in,
                              void* d_out, int out_size, void* d_ws, size_t ws_size,
                              hipStream_t stream) {
    const float* emb      = (const float*)d_in[0];  // (B,S,A,DH) f32
    const int*   sel_idx  = (const int*)d_in[1];    // (B,S,A) i32
    const float* sel_prob = (const float*)d_in[2];  // (B,S,A) f32
    const float* W        = (const float*)d_in[3];  // (H,DH,DM) f32
    const float* bias     = (const float*)d_in[4];  // (H,DM) f32
    float* out = (float*)d_out;

    char* ws = (char*)d_ws;
    int* ctrl   = (int*)(ws + 0);
    int* hist   = (int*)(ws + 0);
    int* offs   = (int*)(ws + 256);
    int* cursor = (int*)(ws + 512);
    int* ntiles = (int*)(ws + 768);
    int* tiles  = (int*)(ws + 1024);
    int* keys   = (int*)(ws + 8192);
    int* perm   = (int*)(ws + 8192 + 65536);
    short* Wt   = (short*)(ws + 262144);
    short* Apk  = (short*)(ws + 4456448);

    k_init<<<dim3(1), dim3(256), 0, stream>>>(ctrl);
    k_keys<<<dim3(T_TOK / 256), dim3(256), 0, stream>>>(sel_idx, keys, hist);
    k_scan<<<dim3(1), dim3(64), 0, stream>>>(hist, offs, tiles, ntiles);
    k_scatter<<<dim3(T_TOK / 256), dim3(256), 0, stream>>>(keys, offs, cursor, perm);
    k_prep<<<dim3(NPACK + 256), dim3(256), 0, stream>>>(
        emb, sel_prob, perm, W, Apk, Wt);
    k_gemm<<<dim3(DMD / 128, 192), dim3(256), 0, stream>>>(
        Apk, sel_prob, Wt, bias, perm, tiles, ntiles, out);
}